// Round 19
// baseline (97.903 us; speedup 1.0000x reference)
//
#include <hip/hip_runtime.h>

typedef __bf16 bf16x8 __attribute__((ext_vector_type(8)));
typedef float  f32x4  __attribute__((ext_vector_type(4)));
typedef float  f32x16 __attribute__((ext_vector_type(16)));
typedef unsigned short u16;
typedef unsigned int u32;
typedef u16 u16x8 __attribute__((ext_vector_type(8)));
typedef u32 u32x4 __attribute__((ext_vector_type(4)));

#define MFMA16(a, b, c) __builtin_amdgcn_mfma_f32_16x16x32_bf16((a), (b), (c), 0, 0, 0)
#define MFMA32(a, b, c) __builtin_amdgcn_mfma_f32_32x32x16_bf16((a), (b), (c), 0, 0, 0)

__device__ __forceinline__ u16 f2bf(float f) {
  __bf16 b = (__bf16)f;
  return __builtin_bit_cast(u16, b);
}
__device__ __forceinline__ bf16x8 ld_bf8(const u16* p) {
  return __builtin_bit_cast(bf16x8, *(const u16x8*)p);
}
__device__ __forceinline__ float ex2(float x) { return __builtin_amdgcn_exp2f(x); }
// v_permlane32_swap_b32 a,b : a' = [a_lo, b_lo], b' = [a_hi, b_hi]
__device__ __forceinline__ void pswap(u32& a, u32& b) {
  asm("v_permlane32_swap_b32 %0, %1" : "+v"(a), "+v"(b));
}

#define GLL(SRC, DST) __builtin_amdgcn_global_load_lds(                     \
    (const __attribute__((address_space(1))) void*)(SRC),                   \
    (__attribute__((address_space(3))) void*)(DST), 16, 0, 0)

// ---------------------------------------------------------------- prep
__global__ __launch_bounds__(256) void k_prep(const float4* __restrict__ x,
                                              ushort4* __restrict__ xb,
                                              const float* __restrict__ Wq,
                                              const float* __restrict__ Wk,
                                              const float* __restrict__ Wv,
                                              const float* __restrict__ Wo,
                                              u16* __restrict__ WqkvT,
                                              u16* __restrict__ WoT,
                                              float2* __restrict__ tab) {
  __shared__ float t[64][65];
  int bid = blockIdx.x;
  if (bid < 4096) {
    int i = bid * 256 + threadIdx.x;
    float4 v = x[i];
    ushort4 o;
    o.x = f2bf(v.x); o.y = f2bf(v.y); o.z = f2bf(v.z); o.w = f2bf(v.w);
    xb[i] = o;
  } else if (bid < 4736) {
    int tb = bid - 4096;
    int n0 = (tb % 40) * 64, k0 = (tb / 40) * 64;
    int c = threadIdx.x & 63, r = threadIdx.x >> 6;
    int n = n0 + c;
    const float* sp; int stride; int nn;
    if (n < 1024)      { sp = Wq; stride = 1024; nn = n; }
    else if (n < 1280) { sp = Wk; stride = 256;  nn = n - 1024; }
    else if (n < 1536) { sp = Wv; stride = 256;  nn = n - 1280; }
    else               { sp = Wo; stride = 1024; nn = n - 1536; }
#pragma unroll
    for (int j = 0; j < 16; ++j)
      t[r + j * 4][c] = sp[(size_t)(k0 + r + j * 4) * stride + nn];
    __syncthreads();
#pragma unroll
    for (int j = 0; j < 16; ++j) {
      int rr = r + j * 4;
      int orow = n0 + rr;
      u16* d = (orow < 1536) ? (WqkvT + (size_t)orow * 1024)
                             : (WoT + (size_t)(orow - 1536) * 1024);
      d[k0 + c] = f2bf(t[c][rr]);
    }
  } else {
    int idx = (bid - 4736) * 256 + threadIdx.x;  // [0, 65536)
    int s = idx >> 5, j = idx & 31;
    const float L2B = 13.287712379549449f / 32.f;  // log2(10000)/32
    float ang = (float)s * exp2f(-(float)j * L2B);
    float sn, cs; sincosf(ang, &sn, &cs);
    tab[idx] = make_float2(cs, sn);
  }
}

// ---------------------------------------------------------------- GEMM1: QKV + fused RoPE
// 64x128 tile (M-split), grid 768 = 3 blocks/CU uniform. (unchanged from r16)
__global__ __launch_bounds__(256) void k_gemm1(const u16* __restrict__ A,
                                               const u16* __restrict__ Bt,
                                               const float2* __restrict__ tab,
                                               u16* __restrict__ Qa,
                                               u16* __restrict__ Ka,
                                               u16* __restrict__ Vtt) {
  const int K = 1024;
  __shared__ u16 lA[64 * 64];
  __shared__ u16 lB[128 * 64];
  const int t = threadIdx.x;
  const int lane = t & 63;
  const int w = t >> 6;
  const int lg = lane >> 4, lr = lane & 15;
  const int wr = w >> 1, wc = w & 1;
  int f = blockIdx.x;
  int cpx = 768 >> 3;
  int f2 = (f & 7) * cpx + (f >> 3);
  const int n0 = (f2 % 12) * 128, m0 = (f2 / 12) * 64;

  f32x4 acc[2][4];
#pragma unroll
  for (int a = 0; a < 2; ++a)
#pragma unroll
    for (int b = 0; b < 4; ++b) acc[a][b] = (f32x4)0.0f;

  for (int kt = 0; kt < K; kt += 64) {
#pragma unroll
    for (int i = 0; i < 2; ++i) {
      int c = t + i * 256;
      int row = c >> 3, slot = c & 7;
      int k8 = (slot ^ (row & 7)) << 3;
      GLL(A + (size_t)(m0 + row) * K + kt + k8, &lA[c * 8]);
    }
#pragma unroll
    for (int i = 0; i < 4; ++i) {
      int c = t + i * 256;
      int row = c >> 3, slot = c & 7;
      int k8 = (slot ^ (row & 7)) << 3;
      GLL(Bt + (size_t)(n0 + row) * K + kt + k8, &lB[c * 8]);
    }
    asm volatile("s_waitcnt vmcnt(0)" ::: "memory");
    __syncthreads();

#pragma unroll
    for (int ks = 0; ks < 2; ++ks) {
      bf16x8 af[2], bff[4];
#pragma unroll
      for (int mf = 0; mf < 2; ++mf) {
        int row = wr * 32 + mf * 16 + lr;
        int eo = (ks * 32 + lg * 8) ^ ((row & 7) << 3);
        af[mf] = ld_bf8(&lA[row * 64 + eo]);
      }
#pragma unroll
      for (int nf = 0; nf < 4; ++nf) {
        int row = wc * 64 + nf * 16 + lr;
        int eo = (ks * 32 + lg * 8) ^ ((row & 7) << 3);
        bff[nf] = ld_bf8(&lB[row * 64 + eo]);
      }
#pragma unroll
      for (int mf = 0; mf < 2; ++mf)
#pragma unroll
        for (int nf = 0; nf < 4; ++nf)
          acc[mf][nf] = MFMA16(af[mf], bff[nf], acc[mf][nf]);
    }
    __syncthreads();
  }

  const int colbase = n0 + wc * 64;
  if (colbase < 1280) {
    const bool isQ = colbase < 1024;
    const float SC = isQ ? 0.18033688f : 1.0f;  // 0.125*log2(e) folded into Q
    u16* base;
    if (isQ) {
      int hh = colbase >> 6;
      base = Qa + (size_t)hh * 2048 * 64;
    } else {
      int kvh = (colbase - 1024) >> 6;
      base = Ka + (size_t)kvh * 2048 * 64;
    }
    const int hstride = isQ ? 16 : 4;
#pragma unroll
    for (int mf = 0; mf < 2; ++mf)
#pragma unroll
      for (int i2 = 0; i2 < 4; ++i2) {
        int row = m0 + wr * 32 + mf * 16 + lg * 4 + i2;
        int bb = row >> 11, ss = row & 2047;
        float2 t0 = tab[ss * 32 + lr];
        float2 t1 = tab[ss * 32 + 16 + lr];
        float v0 = acc[mf][0][i2], v2 = acc[mf][2][i2];
        float v1 = acc[mf][1][i2], v3 = acc[mf][3][i2];
        u16* dst = base + ((size_t)bb * hstride * 2048 + ss) * 64;
        dst[lr]      = f2bf((v0 * t0.x - v2 * t0.y) * SC);
        dst[lr + 32] = f2bf((v2 * t0.x + v0 * t0.y) * SC);
        dst[lr + 16] = f2bf((v1 * t1.x - v3 * t1.y) * SC);
        dst[lr + 48] = f2bf((v3 * t1.x + v1 * t1.y) * SC);
      }
  } else {
    int kvh = (colbase - 1280) >> 6;
#pragma unroll
    for (int mf = 0; mf < 2; ++mf)
#pragma unroll
      for (int i2 = 0; i2 < 4; ++i2) {
        int row = m0 + wr * 32 + mf * 16 + lg * 4 + i2;
        int bb = row >> 11, ss = row & 2047;
        u16* dst = Vtt + (size_t)(bb * 4 + kvh) * 131072 +
                   (size_t)(ss >> 5) * 2048 + (ss & 31);
#pragma unroll
        for (int nf = 0; nf < 4; ++nf)
          dst[(nf * 16 + lr) * 32] = f2bf(acc[mf][nf][i2]);
      }
  }
}

// ---------------------------------------------------------------- flash attention v15
// = r17 structure (shared accumulators) with EQUAL-WORK pairing: blocks i and
// i+256 (observed co-resident on the same CU, same XCD) now carry the SAME qb
// (different bh), so both run in lockstep for their whole lifetime at 2
// waves/SIMD. The r13 complementary pairing balanced total slots but left the
// long block running ALONE for most of its life (short partner exits early) —
// that solo phase was the persistent ~53% idle.
#define PK2(a, b) ((u32)f2bf(a) | ((u32)f2bf(b) << 16))

#define STAGE(DB, J2) do {                                                  \
    GLL(ksrc0 + (size_t)(J2) * 4096,        &kbuf[DB][t * 8]);              \
    GLL(ksrc0 + (size_t)(J2) * 4096 + 2048, &kbuf[DB][2048 + t * 8]);       \
    GLL(vsrc0 + (size_t)(J2) * 4096,        &vbuf[DB][t * 8]);              \
    GLL(vsrc0 + (size_t)(J2) * 4096 + 2048, &vbuf[DB][2048 + t * 8]);       \
  } while (0)

// one 32-kv sub-tile: QK^T (2x 2-deep MFMA chains) -> exp2 -> pack/permlane -> PV
#define SUBC(SOFF, KB, QLIM) do {                                           \
    bf16x8 KF0 = ld_bf8(kb_ + (SOFF) + ql * 64 + (((0 + hi) ^ (ql & 7)) << 3)); \
    bf16x8 KF1 = ld_bf8(kb_ + (SOFF) + ql * 64 + (((2 + hi) ^ (ql & 7)) << 3)); \
    bf16x8 KF2 = ld_bf8(kb_ + (SOFF) + ql * 64 + (((4 + hi) ^ (ql & 7)) << 3)); \
    bf16x8 KF3 = ld_bf8(kb_ + (SOFF) + ql * 64 + (((6 + hi) ^ (ql & 7)) << 3)); \
    bf16x8 VF0 = ld_bf8(vb_ + (SOFF) + ql * 32 + (((0 + hi) ^ (ql & 3)) << 3)); \
    bf16x8 VF1 = ld_bf8(vb_ + (SOFF) + ql * 32 + (((2 + hi) ^ (ql & 3)) << 3)); \
    bf16x8 VF2 = ld_bf8(vb_ + (SOFF) + (32 + ql) * 32 + (((0 + hi) ^ (ql & 3)) << 3)); \
    bf16x8 VF3 = ld_bf8(vb_ + (SOFF) + (32 + ql) * 32 + (((2 + hi) ^ (ql & 3)) << 3)); \
    f32x16 sa_ = MFMA32(KF0, qf0, (f32x16)0.0f);                            \
    sa_ = MFMA32(KF1, qf1, sa_);                                            \
    f32x16 sb_ = MFMA32(KF2, qf2, (f32x16)0.0f);                            \
    sb_ = MFMA32(KF3, qf3, sb_);                                            \
    float p_[16];                                                           \
    _Pragma("unroll")                                                       \
    for (int r = 0; r < 16; ++r) {                                          \
      int kc = (KB) + (r & 3) + 8 * (r >> 2);                               \
      float sv = sa_[r] + sb_[r];                                           \
      p_[r] = (kc > (QLIM)) ? 0.f : ex2(sv);                                \
    }                                                                       \
    { float t0_ = p_[0] + p_[1], t1_ = p_[2] + p_[3];                       \
      float t2_ = p_[4] + p_[5], t3_ = p_[6] + p_[7];                       \
      float t4_ = p_[8] + p_[9], t5_ = p_[10] + p_[11];                     \
      float t6_ = p_[12] + p_[13], t7_ = p_[14] + p_[15];                   \
      lh += ((t0_ + t1_) + (t2_ + t3_)) + ((t4_ + t5_) + (t6_ + t7_)); }    \
    u32 a0 = PK2(p_[0], p_[1]),   a1 = PK2(p_[2], p_[3]);                   \
    u32 a2 = PK2(p_[4], p_[5]),   a3 = PK2(p_[6], p_[7]);                   \
    u32 c0 = PK2(p_[8], p_[9]),   c1 = PK2(p_[10], p_[11]);                 \
    u32 c2 = PK2(p_[12], p_[13]), c3 = PK2(p_[14], p_[15]);                 \
    pswap(a0, a2); pswap(a1, a3); pswap(c0, c2); pswap(c1, c3);             \
    u32x4 w0_, w1_;                                                         \
    w0_.x = a0; w0_.y = a1; w0_.z = a2; w0_.w = a3;                         \
    w1_.x = c0; w1_.y = c1; w1_.z = c2; w1_.w = c3;                         \
    bf16x8 pf0 = __builtin_bit_cast(bf16x8, w0_);                           \
    bf16x8 pf1 = __builtin_bit_cast(bf16x8, w1_);                           \
    o0 = MFMA32(VF0, pf0, o0);                                              \
    o0 = MFMA32(VF1, pf1, o0);                                              \
    o1 = MFMA32(VF2, pf0, o1);                                              \
    o1 = MFMA32(VF3, pf1, o1);                                              \
  } while (0)

__global__ __launch_bounds__(256) void k_attn(const u16* __restrict__ Qa,
                                              const u16* __restrict__ Ka,
                                              const u16* __restrict__ Vtt,
                                              u16* __restrict__ Ob) {
  __shared__ u16 kbuf[4][4096];
  __shared__ u16 vbuf[4][4096];
  const int bid = blockIdx.x;
  // EQUAL-WORK pairing: bid and bid+256 share the same qb (different bh).
  // bid<256: bh 0..15 ; bid>=256: bh 16..31. Longest qb dispatched first.
  const int qb = 15 - ((bid >> 4) & 15);
  const int bh = (bid & 15) | ((bid >> 8) << 4);
  const int h = bh & 15, b = bh >> 4;
  const int kvh = h >> 2;
  const int t = threadIdx.x;
  const int w = t >> 6;
  const int lane = t & 63;
  const int ql = lane & 31;
  const int hi = lane >> 5;
  const int nt2 = qb * 2 + 2;           // staged 64-kv tiles per block
  const int jdw = qb * 4 + w;           // wave's diagonal 32-kv tile
  const int jd2 = jdw >> 1;             // wave's diagonal 64-kv tile
  const int q0w = jdw * 32;
  const int qad = q0w + ql - 4 * hi;

  const u16* Qp = Qa + (size_t)(b * 16 + h) * 2048 * 64;
  const u16* Kp = Ka + (size_t)(b * 4 + kvh) * 2048 * 64;
  const u16* Vp = Vtt + (size_t)(b * 4 + kvh) * 131072;

  // staging source addresses (pre-swizzled; LINEAR LDS dest = swizzled image)
  const u16* ksrc0 = Kp + (size_t)(t >> 3) * 64 + (((t & 7) ^ ((t >> 3) & 7)) << 3);
  const u16* vsrc0 = Vp + (size_t)(t >> 2) * 32 + (((t & 3) ^ ((t >> 2) & 3)) << 3);

  bf16x8 qf0, qf1, qf2, qf3;
  {
    const u16* qp = Qp + (size_t)(q0w + ql) * 64 + hi * 8;
    qf0 = ld_bf8(qp);      qf1 = ld_bf8(qp + 16);
    qf2 = ld_bf8(qp + 32); qf3 = ld_bf8(qp + 48);
  }

  f32x16 o0 = (f32x16)0.0f, o1 = (f32x16)0.0f;
  float lh = 0.f;

  STAGE(0, 0);
  STAGE(1, 1);                          // nt2 >= 2 always
  for (int j2 = 0; j2 < nt2; ++j2) {
    if (j2 + 2 < nt2) STAGE((j2 + 2) & 3, j2 + 2);
    const int infl = min(j2 + 2, nt2 - 1) - j2;   // stages allowed in flight
    if (infl >= 2)      asm volatile("s_waitcnt vmcnt(8)" ::: "memory");
    else if (infl == 1) asm volatile("s_waitcnt vmcnt(4)" ::: "memory");
    else                asm volatile("s_waitcnt vmcnt(0)" ::: "memory");
    __builtin_amdgcn_s_barrier();
    __builtin_amdgcn_sched_barrier(0);
    __builtin_amdgcn_s_setprio(1);
    const u16* kb_ = kbuf[j2 & 3];
    const u16* vb_ = vbuf[j2 & 3];
    if (j2 < jd2) {
      SUBC(0, 0, 0x7fffffff);
      SUBC(2048, 0, 0x7fffffff);
    } else if (j2 == jd2) {
      SUBC(0, jd2 * 64, (jdw & 1) ? 0x7fffffff : qad);
      if (jdw & 1) SUBC(2048, jd2 * 64 + 32, qad);
    }
    __builtin_amdgcn_s_setprio(0);
  }

  float l = lh + __shfl_xor(lh, 32);
  float li = 1.f / l;
  u16* op = Ob + ((size_t)(b * 2048 + q0w + ql)) * 1024 + h * 64 + hi * 4;
#pragma unroll
  for (int g = 0; g < 4; ++g) {
    ushort4 wv;
    wv.x = f2bf(o0[g * 4 + 0] * li); wv.y = f2bf(o0[g * 4 + 1] * li);
    wv.z = f2bf(o0[g * 4 + 2] * li); wv.w = f2bf(o0[g * 4 + 3] * li);
    *(ushort4*)(op + g * 8) = wv;
    wv.x = f2bf(o1[g * 4 + 0] * li); wv.y = f2bf(o1[g * 4 + 1] * li);
    wv.z = f2bf(o1[g * 4 + 2] * li); wv.w = f2bf(o1[g * 4 + 3] * li);
    *(ushort4*)(op + 32 + g * 8) = wv;
  }
}

// ---------------------------------------------------------------- GEMM2 (out proj)
// 64x128 tile (M-split), grid 512 = 2 blocks/CU uniform. (unchanged from r17)
__global__ __launch_bounds__(256) void k_gemm2(const u16* __restrict__ A,
                                               const u16* __restrict__ Bt,
                                               float* __restrict__ C) {
  const int K = 1024, N = 1024;
  __shared__ u16 lA[64 * 64];
  __shared__ u16 lB[128 * 64];
  const int t = threadIdx.x;
  const int lane = t & 63;
  const int w = t >> 6;
  const int lg = lane >> 4, lr = lane & 15;
  const int wr = w >> 1, wc = w & 1;
  int f = blockIdx.x;
  int cpx = 512 >> 3;
  int f2 = (f & 7) * cpx + (f >> 3);
  const int n0 = (f2 & 7) * 128, m0 = (f2 >> 3) * 64;

  f32x4 acc[2][4];
#pragma unroll
  for (int a = 0; a < 2; ++a)
#pragma unroll
    for (int b = 0; b < 4; ++b) acc[a][b] = (f32x4)0.0f;

  for (int kt = 0; kt < K; kt += 64) {
#pragma unroll
    for (int i = 0; i < 2; ++i) {
      int c = t + i * 256;
      int row = c >> 3, slot = c & 7;
      int k8 = (slot ^ (row & 7)) << 3;
      GLL(A + (size_t)(m0 + row) * K + kt + k8, &lA[c * 8]);
    }
#pragma unroll
    for (int i = 0; i < 4; ++i) {
      int c = t + i * 256;
      int row = c >> 3, slot = c & 7;
      int k8 = (slot ^ (row & 7)) << 3;
      GLL(Bt + (size_t)(n0 + row) * K + kt + k8, &lB[c * 8]);
    }
    asm volatile("s_waitcnt vmcnt(0)" ::: "memory");
    __syncthreads();

#pragma unroll
    for (int ks = 0; ks < 2; ++ks) {
      bf16x8 af[2], bff[4];
#pragma unroll
      for (int mf = 0; mf < 2; ++mf) {
        int row = wr * 32 + mf * 16 + lr;
        int eo = (ks * 32 + lg * 8) ^ ((row & 7) << 3);
        af[mf] = ld_bf8(&lA[row * 64 + eo]);
      }
#pragma unroll
      for (int nf = 0; nf < 4; ++nf) {
        int row = wc * 64 + nf * 16 + lr;
        int eo = (ks * 32 + lg * 8) ^ ((row & 7) << 3);
        bff[nf] = ld_bf8(&lB[row * 64 + eo]);
      }
#pragma unroll
      for (int mf = 0; mf < 2; ++mf)
#pragma unroll
        for (int nf = 0; nf < 4; ++nf)
          acc[mf][nf] = MFMA16(af[mf], bff[nf], acc[mf][nf]);
    }
    __syncthreads();
  }

#pragma unroll
  for (int mf = 0; mf < 2; ++mf)
#pragma unroll
    for (int nf = 0; nf < 4; ++nf) {
      int col = n0 + wc * 64 + nf * 16 + lr;
#pragma unroll
      for (int i = 0; i < 4; ++i) {
        int row = m0 + wr * 32 + mf * 16 + lg * 4 + i;
        C[(size_t)row * N + col] = acc[mf][nf][i];
      }
    }
}

// ----------------------------------------------------------------------------
extern "C" void kernel_launch(void* const* d_in, const int* in_sizes, int n_in,
                              void* d_out, int out_size, void* d_ws, size_t ws_size,
                              hipStream_t stream) {
  const float* x  = (const float*)d_in[0];
  const float* Wq = (const float*)d_in[1];
  const float* Wk = (const float*)d_in[2];
  const float* Wv = (const float*)d_in[3];
  const float* Wo = (const float*)d_in[4];
  float* out = (float*)d_out;

  char* ws = (char*)d_ws;
  u16*    xb    = (u16*)(ws);                    //  8,388,608
  u16*    WqkvT = (u16*)(ws + 8388608);          //  3,145,728
  u16*    WoT   = (u16*)(ws + 11534336);         //  2,097,152
  float2* tab   = (float2*)(ws + 13631488);      //    524,288
  u16*    Qa    = (u16*)(ws + 14155776);         //  8,388,608
  u16*    Ka    = (u16*)(ws + 22544384);         //  2,097,152
  u16*    Vtt   = (u16*)(ws + 26738688);         //  2,097,152
  u16*    Ob    = (u16*)(ws + 28835840);         //  8,388,608  (end 37,224,448)

  k_prep<<<4992, 256, 0, stream>>>((const float4*)x, (ushort4*)xb, Wq, Wk, Wv, Wo,
                                   WqkvT, WoT, tab);
  k_gemm1<<<768, 256, 0, stream>>>(xb, WqkvT, tab, Qa, Ka, Vtt);
  k_attn<<<512, 256, 0, stream>>>(Qa, Ka, Vtt, Ob);
  k_gemm2<<<512, 256, 0, stream>>>(Ob, WoT, out);
}

// Round 20
// 85.253 us; speedup vs baseline: 1.1484x; 1.1484x over previous
//
#include <hip/hip_runtime.h>

typedef __bf16 bf16x8 __attribute__((ext_vector_type(8)));
typedef float  f32x4  __attribute__((ext_vector_type(4)));
typedef float  f32x16 __attribute__((ext_vector_type(16)));
typedef unsigned short u16;
typedef unsigned int u32;
typedef u16 u16x8 __attribute__((ext_vector_type(8)));
typedef u32 u32x4 __attribute__((ext_vector_type(4)));

#define MFMA16(a, b, c) __builtin_amdgcn_mfma_f32_16x16x32_bf16((a), (b), (c), 0, 0, 0)
#define MFMA32(a, b, c) __builtin_amdgcn_mfma_f32_32x32x16_bf16((a), (b), (c), 0, 0, 0)

__device__ __forceinline__ u16 f2bf(float f) {
  __bf16 b = (__bf16)f;
  return __builtin_bit_cast(u16, b);
}
__device__ __forceinline__ bf16x8 ld_bf8(const u16* p) {
  return __builtin_bit_cast(bf16x8, *(const u16x8*)p);
}
__device__ __forceinline__ float ex2(float x) { return __builtin_amdgcn_exp2f(x); }
// v_permlane32_swap_b32 a,b : a' = [a_lo, b_lo], b' = [a_hi, b_hi]
__device__ __forceinline__ void pswap(u32& a, u32& b) {
  asm("v_permlane32_swap_b32 %0, %1" : "+v"(a), "+v"(b));
}

#define GLL(SRC, DST) __builtin_amdgcn_global_load_lds(                     \
    (const __attribute__((address_space(1))) void*)(SRC),                   \
    (__attribute__((address_space(3))) void*)(DST), 16, 0, 0)

// ---------------------------------------------------------------- prep
__global__ __launch_bounds__(256) void k_prep(const float4* __restrict__ x,
                                              ushort4* __restrict__ xb,
                                              const float* __restrict__ Wq,
                                              const float* __restrict__ Wk,
                                              const float* __restrict__ Wv,
                                              const float* __restrict__ Wo,
                                              u16* __restrict__ WqkvT,
                                              u16* __restrict__ WoT,
                                              float2* __restrict__ tab) {
  __shared__ float t[64][65];
  int bid = blockIdx.x;
  if (bid < 4096) {
    int i = bid * 256 + threadIdx.x;
    float4 v = x[i];
    ushort4 o;
    o.x = f2bf(v.x); o.y = f2bf(v.y); o.z = f2bf(v.z); o.w = f2bf(v.w);
    xb[i] = o;
  } else if (bid < 4736) {
    int tb = bid - 4096;
    int n0 = (tb % 40) * 64, k0 = (tb / 40) * 64;
    int c = threadIdx.x & 63, r = threadIdx.x >> 6;
    int n = n0 + c;
    const float* sp; int stride; int nn;
    if (n < 1024)      { sp = Wq; stride = 1024; nn = n; }
    else if (n < 1280) { sp = Wk; stride = 256;  nn = n - 1024; }
    else if (n < 1536) { sp = Wv; stride = 256;  nn = n - 1280; }
    else               { sp = Wo; stride = 1024; nn = n - 1536; }
#pragma unroll
    for (int j = 0; j < 16; ++j)
      t[r + j * 4][c] = sp[(size_t)(k0 + r + j * 4) * stride + nn];
    __syncthreads();
#pragma unroll
    for (int j = 0; j < 16; ++j) {
      int rr = r + j * 4;
      int orow = n0 + rr;
      u16* d = (orow < 1536) ? (WqkvT + (size_t)orow * 1024)
                             : (WoT + (size_t)(orow - 1536) * 1024);
      d[k0 + c] = f2bf(t[c][rr]);
    }
  } else {
    int idx = (bid - 4736) * 256 + threadIdx.x;  // [0, 65536)
    int s = idx >> 5, j = idx & 31;
    const float L2B = 13.287712379549449f / 32.f;  // log2(10000)/32
    float ang = (float)s * exp2f(-(float)j * L2B);
    float sn, cs; sincosf(ang, &sn, &cs);
    tab[idx] = make_float2(cs, sn);
  }
}

// ---------------------------------------------------------------- GEMM1: QKV + fused RoPE
// 64x128 tile (M-split), grid 768 = 3 blocks/CU uniform.
__global__ __launch_bounds__(256) void k_gemm1(const u16* __restrict__ A,
                                               const u16* __restrict__ Bt,
                                               const float2* __restrict__ tab,
                                               u16* __restrict__ Qa,
                                               u16* __restrict__ Ka,
                                               u16* __restrict__ Vtt) {
  const int K = 1024;
  __shared__ u16 lA[64 * 64];
  __shared__ u16 lB[128 * 64];
  const int t = threadIdx.x;
  const int lane = t & 63;
  const int w = t >> 6;
  const int lg = lane >> 4, lr = lane & 15;
  const int wr = w >> 1, wc = w & 1;
  int f = blockIdx.x;
  int cpx = 768 >> 3;
  int f2 = (f & 7) * cpx + (f >> 3);
  const int n0 = (f2 % 12) * 128, m0 = (f2 / 12) * 64;

  f32x4 acc[2][4];
#pragma unroll
  for (int a = 0; a < 2; ++a)
#pragma unroll
    for (int b = 0; b < 4; ++b) acc[a][b] = (f32x4)0.0f;

  for (int kt = 0; kt < K; kt += 64) {
#pragma unroll
    for (int i = 0; i < 2; ++i) {
      int c = t + i * 256;
      int row = c >> 3, slot = c & 7;
      int k8 = (slot ^ (row & 7)) << 3;
      GLL(A + (size_t)(m0 + row) * K + kt + k8, &lA[c * 8]);
    }
#pragma unroll
    for (int i = 0; i < 4; ++i) {
      int c = t + i * 256;
      int row = c >> 3, slot = c & 7;
      int k8 = (slot ^ (row & 7)) << 3;
      GLL(Bt + (size_t)(n0 + row) * K + kt + k8, &lB[c * 8]);
    }
    asm volatile("s_waitcnt vmcnt(0)" ::: "memory");
    __syncthreads();

#pragma unroll
    for (int ks = 0; ks < 2; ++ks) {
      bf16x8 af[2], bff[4];
#pragma unroll
      for (int mf = 0; mf < 2; ++mf) {
        int row = wr * 32 + mf * 16 + lr;
        int eo = (ks * 32 + lg * 8) ^ ((row & 7) << 3);
        af[mf] = ld_bf8(&lA[row * 64 + eo]);
      }
#pragma unroll
      for (int nf = 0; nf < 4; ++nf) {
        int row = wc * 64 + nf * 16 + lr;
        int eo = (ks * 32 + lg * 8) ^ ((row & 7) << 3);
        bff[nf] = ld_bf8(&lB[row * 64 + eo]);
      }
#pragma unroll
      for (int mf = 0; mf < 2; ++mf)
#pragma unroll
        for (int nf = 0; nf < 4; ++nf)
          acc[mf][nf] = MFMA16(af[mf], bff[nf], acc[mf][nf]);
    }
    __syncthreads();
  }

  const int colbase = n0 + wc * 64;
  if (colbase < 1280) {
    const bool isQ = colbase < 1024;
    const float SC = isQ ? 0.18033688f : 1.0f;  // 0.125*log2(e) folded into Q
    u16* base;
    if (isQ) {
      int hh = colbase >> 6;
      base = Qa + (size_t)hh * 2048 * 64;
    } else {
      int kvh = (colbase - 1024) >> 6;
      base = Ka + (size_t)kvh * 2048 * 64;
    }
    const int hstride = isQ ? 16 : 4;
#pragma unroll
    for (int mf = 0; mf < 2; ++mf)
#pragma unroll
      for (int i2 = 0; i2 < 4; ++i2) {
        int row = m0 + wr * 32 + mf * 16 + lg * 4 + i2;
        int bb = row >> 11, ss = row & 2047;
        float2 t0 = tab[ss * 32 + lr];
        float2 t1 = tab[ss * 32 + 16 + lr];
        float v0 = acc[mf][0][i2], v2 = acc[mf][2][i2];
        float v1 = acc[mf][1][i2], v3 = acc[mf][3][i2];
        u16* dst = base + ((size_t)bb * hstride * 2048 + ss) * 64;
        dst[lr]      = f2bf((v0 * t0.x - v2 * t0.y) * SC);
        dst[lr + 32] = f2bf((v2 * t0.x + v0 * t0.y) * SC);
        dst[lr + 16] = f2bf((v1 * t1.x - v3 * t1.y) * SC);
        dst[lr + 48] = f2bf((v3 * t1.x + v1 * t1.y) * SC);
      }
  } else {
    int kvh = (colbase - 1280) >> 6;
#pragma unroll
    for (int mf = 0; mf < 2; ++mf)
#pragma unroll
      for (int i2 = 0; i2 < 4; ++i2) {
        int row = m0 + wr * 32 + mf * 16 + lg * 4 + i2;
        int bb = row >> 11, ss = row & 2047;
        u16* dst = Vtt + (size_t)(bb * 4 + kvh) * 131072 +
                   (size_t)(ss >> 5) * 2048 + (ss & 31);
#pragma unroll
        for (int nf = 0; nf < 4; ++nf)
          dst[(nf * 16 + lr) * 32] = f2bf(acc[mf][nf][i2]);
      }
  }
}

// ---------------------------------------------------------------- flash attention v13
// r14/r17 config: 4-deep ring, one barrier/iter, counted vmcnt, setprio,
// complementary pairing (optimal for unsplit blocks per the c1/c2 model).
#define PK2(a, b) ((u32)f2bf(a) | ((u32)f2bf(b) << 16))

#define STAGE(DB, J2) do {                                                  \
    GLL(ksrc0 + (size_t)(J2) * 4096,        &kbuf[DB][t * 8]);              \
    GLL(ksrc0 + (size_t)(J2) * 4096 + 2048, &kbuf[DB][2048 + t * 8]);       \
    GLL(vsrc0 + (size_t)(J2) * 4096,        &vbuf[DB][t * 8]);              \
    GLL(vsrc0 + (size_t)(J2) * 4096 + 2048, &vbuf[DB][2048 + t * 8]);       \
  } while (0)

// one 32-kv sub-tile: QK^T (2x 2-deep MFMA chains) -> exp2 -> pack/permlane -> PV
#define SUBC(SOFF, KB, QLIM) do {                                           \
    bf16x8 KF0 = ld_bf8(kb_ + (SOFF) + ql * 64 + (((0 + hi) ^ (ql & 7)) << 3)); \
    bf16x8 KF1 = ld_bf8(kb_ + (SOFF) + ql * 64 + (((2 + hi) ^ (ql & 7)) << 3)); \
    bf16x8 KF2 = ld_bf8(kb_ + (SOFF) + ql * 64 + (((4 + hi) ^ (ql & 7)) << 3)); \
    bf16x8 KF3 = ld_bf8(kb_ + (SOFF) + ql * 64 + (((6 + hi) ^ (ql & 7)) << 3)); \
    bf16x8 VF0 = ld_bf8(vb_ + (SOFF) + ql * 32 + (((0 + hi) ^ (ql & 3)) << 3)); \
    bf16x8 VF1 = ld_bf8(vb_ + (SOFF) + ql * 32 + (((2 + hi) ^ (ql & 3)) << 3)); \
    bf16x8 VF2 = ld_bf8(vb_ + (SOFF) + (32 + ql) * 32 + (((0 + hi) ^ (ql & 3)) << 3)); \
    bf16x8 VF3 = ld_bf8(vb_ + (SOFF) + (32 + ql) * 32 + (((2 + hi) ^ (ql & 3)) << 3)); \
    f32x16 sa_ = MFMA32(KF0, qf0, (f32x16)0.0f);                            \
    sa_ = MFMA32(KF1, qf1, sa_);                                            \
    f32x16 sb_ = MFMA32(KF2, qf2, (f32x16)0.0f);                            \
    sb_ = MFMA32(KF3, qf3, sb_);                                            \
    float p_[16];                                                           \
    _Pragma("unroll")                                                       \
    for (int r = 0; r < 16; ++r) {                                          \
      int kc = (KB) + (r & 3) + 8 * (r >> 2);                               \
      float sv = sa_[r] + sb_[r];                                           \
      p_[r] = (kc > (QLIM)) ? 0.f : ex2(sv);                                \
    }                                                                       \
    { float t0_ = p_[0] + p_[1], t1_ = p_[2] + p_[3];                       \
      float t2_ = p_[4] + p_[5], t3_ = p_[6] + p_[7];                       \
      float t4_ = p_[8] + p_[9], t5_ = p_[10] + p_[11];                     \
      float t6_ = p_[12] + p_[13], t7_ = p_[14] + p_[15];                   \
      lh += ((t0_ + t1_) + (t2_ + t3_)) + ((t4_ + t5_) + (t6_ + t7_)); }    \
    u32 a0 = PK2(p_[0], p_[1]),   a1 = PK2(p_[2], p_[3]);                   \
    u32 a2 = PK2(p_[4], p_[5]),   a3 = PK2(p_[6], p_[7]);                   \
    u32 c0 = PK2(p_[8], p_[9]),   c1 = PK2(p_[10], p_[11]);                 \
    u32 c2 = PK2(p_[12], p_[13]), c3 = PK2(p_[14], p_[15]);                 \
    pswap(a0, a2); pswap(a1, a3); pswap(c0, c2); pswap(c1, c3);             \
    u32x4 w0_, w1_;                                                         \
    w0_.x = a0; w0_.y = a1; w0_.z = a2; w0_.w = a3;                         \
    w1_.x = c0; w1_.y = c1; w1_.z = c2; w1_.w = c3;                         \
    bf16x8 pf0 = __builtin_bit_cast(bf16x8, w0_);                           \
    bf16x8 pf1 = __builtin_bit_cast(bf16x8, w1_);                           \
    o0 = MFMA32(VF0, pf0, o0);                                              \
    o0 = MFMA32(VF1, pf1, o0);                                              \
    o1 = MFMA32(VF2, pf0, o1);                                              \
    o1 = MFMA32(VF3, pf1, o1);                                              \
  } while (0)

__global__ __launch_bounds__(256) void k_attn(const u16* __restrict__ Qa,
                                              const u16* __restrict__ Ka,
                                              const u16* __restrict__ Vtt,
                                              u16* __restrict__ Ob) {
  __shared__ u16 kbuf[4][4096];
  __shared__ u16 vbuf[4][4096];
  const int bid = blockIdx.x;
  // complementary pairing: bid<256 -> qb 15..8 ; bid>=256 -> qb 0..7.
  // CU_i's pair (i, i+256) sums to a constant 34 iteration-slots.
  const int qb = (bid < 256) ? (15 - (bid >> 5)) : ((bid - 256) >> 5);
  const int bh = bid & 31;
  const int h = bh & 15, b = bh >> 4;
  const int kvh = h >> 2;
  const int t = threadIdx.x;
  const int w = t >> 6;
  const int lane = t & 63;
  const int ql = lane & 31;
  const int hi = lane >> 5;
  const int nt2 = qb * 2 + 2;           // staged 64-kv tiles per block
  const int jdw = qb * 4 + w;           // wave's diagonal 32-kv tile
  const int jd2 = jdw >> 1;             // wave's diagonal 64-kv tile
  const int q0w = jdw * 32;
  const int qad = q0w + ql - 4 * hi;

  const u16* Qp = Qa + (size_t)(b * 16 + h) * 2048 * 64;
  const u16* Kp = Ka + (size_t)(b * 4 + kvh) * 2048 * 64;
  const u16* Vp = Vtt + (size_t)(b * 4 + kvh) * 131072;

  // staging source addresses (pre-swizzled; LINEAR LDS dest = swizzled image)
  const u16* ksrc0 = Kp + (size_t)(t >> 3) * 64 + (((t & 7) ^ ((t >> 3) & 7)) << 3);
  const u16* vsrc0 = Vp + (size_t)(t >> 2) * 32 + (((t & 3) ^ ((t >> 2) & 3)) << 3);

  bf16x8 qf0, qf1, qf2, qf3;
  {
    const u16* qp = Qp + (size_t)(q0w + ql) * 64 + hi * 8;
    qf0 = ld_bf8(qp);      qf1 = ld_bf8(qp + 16);
    qf2 = ld_bf8(qp + 32); qf3 = ld_bf8(qp + 48);
  }

  f32x16 o0 = (f32x16)0.0f, o1 = (f32x16)0.0f;
  float lh = 0.f;

  STAGE(0, 0);
  STAGE(1, 1);                          // nt2 >= 2 always
  for (int j2 = 0; j2 < nt2; ++j2) {
    if (j2 + 2 < nt2) STAGE((j2 + 2) & 3, j2 + 2);
    const int infl = min(j2 + 2, nt2 - 1) - j2;   // stages allowed in flight
    if (infl >= 2)      asm volatile("s_waitcnt vmcnt(8)" ::: "memory");
    else if (infl == 1) asm volatile("s_waitcnt vmcnt(4)" ::: "memory");
    else                asm volatile("s_waitcnt vmcnt(0)" ::: "memory");
    __builtin_amdgcn_s_barrier();
    __builtin_amdgcn_sched_barrier(0);
    __builtin_amdgcn_s_setprio(1);
    const u16* kb_ = kbuf[j2 & 3];
    const u16* vb_ = vbuf[j2 & 3];
    if (j2 < jd2) {
      SUBC(0, 0, 0x7fffffff);
      SUBC(2048, 0, 0x7fffffff);
    } else if (j2 == jd2) {
      SUBC(0, jd2 * 64, (jdw & 1) ? 0x7fffffff : qad);
      if (jdw & 1) SUBC(2048, jd2 * 64 + 32, qad);
    }
    __builtin_amdgcn_s_setprio(0);
  }

  float l = lh + __shfl_xor(lh, 32);
  float li = 1.f / l;
  u16* op = Ob + ((size_t)(b * 2048 + q0w + ql)) * 1024 + h * 64 + hi * 4;
#pragma unroll
  for (int g = 0; g < 4; ++g) {
    ushort4 wv;
    wv.x = f2bf(o0[g * 4 + 0] * li); wv.y = f2bf(o0[g * 4 + 1] * li);
    wv.z = f2bf(o0[g * 4 + 2] * li); wv.w = f2bf(o0[g * 4 + 3] * li);
    *(ushort4*)(op + g * 8) = wv;
    wv.x = f2bf(o1[g * 4 + 0] * li); wv.y = f2bf(o1[g * 4 + 1] * li);
    wv.z = f2bf(o1[g * 4 + 2] * li); wv.w = f2bf(o1[g * 4 + 3] * li);
    *(ushort4*)(op + 32 + g * 8) = wv;
  }
}

// ---------------------------------------------------------------- GEMM2 (out proj)
// 64x128 tile (M-split), grid 512 = 2 blocks/CU uniform.
__global__ __launch_bounds__(256) void k_gemm2(const u16* __restrict__ A,
                                               const u16* __restrict__ Bt,
                                               float* __restrict__ C) {
  const int K = 1024, N = 1024;
  __shared__ u16 lA[64 * 64];
  __shared__ u16 lB[128 * 64];
  const int t = threadIdx.x;
  const int lane = t & 63;
  const int w = t >> 6;
  const int lg = lane >> 4, lr = lane & 15;
  const int wr = w >> 1, wc = w & 1;
  int f = blockIdx.x;
  int cpx = 512 >> 3;
  int f2 = (f & 7) * cpx + (f >> 3);
  const int n0 = (f2 & 7) * 128, m0 = (f2 >> 3) * 64;

  f32x4 acc[2][4];
#pragma unroll
  for (int a = 0; a < 2; ++a)
#pragma unroll
    for (int b = 0; b < 4; ++b) acc[a][b] = (f32x4)0.0f;

  for (int kt = 0; kt < K; kt += 64) {
#pragma unroll
    for (int i = 0; i < 2; ++i) {
      int c = t + i * 256;
      int row = c >> 3, slot = c & 7;
      int k8 = (slot ^ (row & 7)) << 3;
      GLL(A + (size_t)(m0 + row) * K + kt + k8, &lA[c * 8]);
    }
#pragma unroll
    for (int i = 0; i < 4; ++i) {
      int c = t + i * 256;
      int row = c >> 3, slot = c & 7;
      int k8 = (slot ^ (row & 7)) << 3;
      GLL(Bt + (size_t)(n0 + row) * K + kt + k8, &lB[c * 8]);
    }
    asm volatile("s_waitcnt vmcnt(0)" ::: "memory");
    __syncthreads();

#pragma unroll
    for (int ks = 0; ks < 2; ++ks) {
      bf16x8 af[2], bff[4];
#pragma unroll
      for (int mf = 0; mf < 2; ++mf) {
        int row = wr * 32 + mf * 16 + lr;
        int eo = (ks * 32 + lg * 8) ^ ((row & 7) << 3);
        af[mf] = ld_bf8(&lA[row * 64 + eo]);
      }
#pragma unroll
      for (int nf = 0; nf < 4; ++nf) {
        int row = wc * 64 + nf * 16 + lr;
        int eo = (ks * 32 + lg * 8) ^ ((row & 7) << 3);
        bff[nf] = ld_bf8(&lB[row * 64 + eo]);
      }
#pragma unroll
      for (int mf = 0; mf < 2; ++mf)
#pragma unroll
        for (int nf = 0; nf < 4; ++nf)
          acc[mf][nf] = MFMA16(af[mf], bff[nf], acc[mf][nf]);
    }
    __syncthreads();
  }

#pragma unroll
  for (int mf = 0; mf < 2; ++mf)
#pragma unroll
    for (int nf = 0; nf < 4; ++nf) {
      int col = n0 + wc * 64 + nf * 16 + lr;
#pragma unroll
      for (int i = 0; i < 4; ++i) {
        int row = m0 + wr * 32 + mf * 16 + lg * 4 + i;
        C[(size_t)row * N + col] = acc[mf][nf][i];
      }
    }
}

// ----------------------------------------------------------------------------
extern "C" void kernel_launch(void* const* d_in, const int* in_sizes, int n_in,
                              void* d_out, int out_size, void* d_ws, size_t ws_size,
                              hipStream_t stream) {
  const float* x  = (const float*)d_in[0];
  const float* Wq = (const float*)d_in[1];
  const float* Wk = (const float*)d_in[2];
  const float* Wv = (const float*)d_in[3];
  const float* Wo = (const float*)d_in[4];
  float* out = (float*)d_out;

  char* ws = (char*)d_ws;
  u16*    xb    = (u16*)(ws);                    //  8,388,608
  u16*    WqkvT = (u16*)(ws + 8388608);          //  3,145,728
  u16*    WoT   = (u16*)(ws + 11534336);         //  2,097,152
  float2* tab   = (float2*)(ws + 13631488);      //    524,288
  u16*    Qa    = (u16*)(ws + 14155776);         //  8,388,608
  u16*    Ka    = (u16*)(ws + 22544384);         //  2,097,152
  u16*    Vtt   = (u16*)(ws + 26738688);         //  2,097,152
  u16*    Ob    = (u16*)(ws + 28835840);         //  8,388,608  (end 37,224,448)

  k_prep<<<4992, 256, 0, stream>>>((const float4*)x, (ushort4*)xb, Wq, Wk, Wv, Wo,
                                   WqkvT, WoT, tab);
  k_gemm1<<<768, 256, 0, stream>>>(xb, WqkvT, tab, Qa, Ka, Vtt);
  k_attn<<<512, 256, 0, stream>>>(Qa, Ka, Vtt, Ob);
  k_gemm2<<<512, 256, 0, stream>>>(Ob, WoT, out);
}